// Round 8
// baseline (3057.692 us; speedup 1.0000x reference)
//
#include <hip/hip_runtime.h>
#include <hip/hip_fp16.h>

typedef _Float16 f16;
typedef _Float16 f16x8 __attribute__((ext_vector_type(8)));
typedef _Float16 f16x4 __attribute__((ext_vector_type(4)));
typedef float f32x4 __attribute__((ext_vector_type(4)));

#define B_ 1024
#define T_ 128
#define F_ 9
#define H_ 256
#define P_ 2048
#define R_ 8

typedef unsigned long long ull;
#define AL(p) __hip_atomic_load((p), __ATOMIC_RELAXED, __HIP_MEMORY_SCOPE_AGENT)
#define AS(p, v) __hip_atomic_store((p), (v), __ATOMIC_RELAXED, __HIP_MEMORY_SCOPE_AGENT)

// ---------------- helpers ----------------
__device__ __forceinline__ float sigf(float x) { return 1.f / (1.f + __expf(-x)); }
__device__ __forceinline__ float tanh_(float x) {
  float a = fminf(fabsf(x), 12.f);
  float e = __expf(2.f * a);
  float r = 1.f - 2.f / (e + 1.f);
  return copysignf(r, x);
}

__device__ __forceinline__ f16x8 aload16(const f16* p) {
  union { ull u[2]; f16x8 v; } r;
  r.u[0] = AL((const ull*)p);
  r.u[1] = AL((const ull*)p + 1);
  return r.v;
}

__device__ __forceinline__ float blk_sum(float v) {
  __shared__ float sh[8];
  int lane = threadIdx.x & 63, w = threadIdx.x >> 6;
  int nw = blockDim.x >> 6;
#pragma unroll
  for (int o = 32; o > 0; o >>= 1) v += __shfl_xor(v, o, 64);
  __syncthreads();
  if (lane == 0) sh[w] = v;
  __syncthreads();
  float t = 0.f;
  for (int i = 0; i < nw; i++) t += sh[i];
  return t;
}

// ---------------- generic fp16 MFMA GEMM ----------------
__global__ __launch_bounds__(256) void gemm_f16(
    const f16* __restrict__ A, int lda,
    const f16* __restrict__ Bt, int ldb,
    const float* __restrict__ bias,
    f16* __restrict__ o16, int ldo16,
    float* __restrict__ o32, int ldo32,
    int M, int N, int K)
{
  __shared__ __align__(16) f16 As[128][40];
  __shared__ __align__(16) f16 Bs[128][40];
  const int tid = threadIdx.x;
  const int lane = tid & 63, wave = tid >> 6;
  const int wr = (wave >> 1) * 64, wc = (wave & 1) * 64;
  const int q = lane >> 4, l15 = lane & 15;
  const int bm = blockIdx.x * 128, bn = blockIdx.y * 128;

  f32x4 acc[4][4];
#pragma unroll
  for (int i = 0; i < 4; i++)
#pragma unroll
    for (int j = 0; j < 4; j++) acc[i][j] = (f32x4){0.f, 0.f, 0.f, 0.f};

  for (int k0 = 0; k0 < K; k0 += 32) {
#pragma unroll
    for (int c = 0; c < 2; ++c) {
      int ch = tid + c * 256;
      int row = ch >> 2, kh = (ch & 3) * 8;
      *(f16x8*)&As[row][kh] = *(const f16x8*)&A[(size_t)(bm + row) * lda + k0 + kh];
      *(f16x8*)&Bs[row][kh] = *(const f16x8*)&Bt[(size_t)(bn + row) * ldb + k0 + kh];
    }
    __syncthreads();
    f16x8 af[4], bf[4];
#pragma unroll
    for (int tm = 0; tm < 4; tm++) af[tm] = *(const f16x8*)&As[wr + tm * 16 + l15][q * 8];
#pragma unroll
    for (int tn = 0; tn < 4; tn++) bf[tn] = *(const f16x8*)&Bs[wc + tn * 16 + l15][q * 8];
#pragma unroll
    for (int tm = 0; tm < 4; tm++)
#pragma unroll
      for (int tn = 0; tn < 4; tn++)
        acc[tm][tn] = __builtin_amdgcn_mfma_f32_16x16x32_f16(af[tm], bf[tn], acc[tm][tn], 0, 0, 0);
    __syncthreads();
  }
#pragma unroll
  for (int tm = 0; tm < 4; tm++) {
#pragma unroll
    for (int tn = 0; tn < 4; tn++) {
      int colg = bn + wc + tn * 16 + l15;
      float bv = bias ? bias[colg] : 0.f;
#pragma unroll
      for (int r = 0; r < 4; r++) {
        int rowg = bm + wr + tm * 16 + q * 4 + r;
        float v = acc[tm][tn][r] + bv;
        if (o32) o32[(size_t)rowg * ldo32 + colg] = v;
        if (o16) o16[(size_t)rowg * ldo16 + colg] = (f16)v;
      }
    }
  }
}

// ---------------- LSTM v9: intra-CU recurrence via role pipeline ----------
// R1..R7 established: any scheme where the 256-wide h crosses CUs every
// step has a ~2.8us/layer-step floor (6 protocol variants bracket it).
// v9 removes the cross-CU recurrence entirely. Each layer splits into:
//   A-block: xp_t = x_t @ Wih^T           (feed-forward, no recurrence)
//   B-block: h_t = gates(xp_t + h_{t-1} @ Whh^T)   (recurrence local!)
// Each block holds ONE 512-KB matrix: 4 K-slices in 256 VGPRs, 1 slice
// LDS-resident, 3 slices streamed from L2 per step (same 192 KB every
// step -> L2-hot). h_{t-1} lives in the B-block's own LDS htile: the
// serial chain is LDS->MFMA->gates->LDS, zero cross-CU round trips.
// Cross-block edges are FORWARD-ONLY (A0->B0->A1->B1) through R=8-deep
// rings with the R6-proven flag protocol (store -> syncthreads drain ->
// tid0 flag-store; consumer tid0 polls -> barrier -> loads). Credits
// (consumer flag >= t-R+1) bound the rings; dependency DAG + R-slack =
// deadlock-free; capped polls bail out (wrong beats hang).
// Geometry: 64 groups x 16 rows x 4 roles = 256 blocks = 1/CU.
// Wave w owns n-tiles {w+4m}: gate g of col-set c is tile w+4(m+4g) ->
// i/f/g/o for one h-col live in one thread's acc (no cross-wave gates).
__global__ __launch_bounds__(256, 1) void lstm4(
    const f16* __restrict__ xA, f16* __restrict__ hOut,
    f16* __restrict__ xp0, f16* __restrict__ xp1, f16* __restrict__ h0r,
    const f16* __restrict__ wrole,
    const float* __restrict__ b0, const float* __restrict__ b1,
    int* __restrict__ flags)
{
  __shared__ f16 wres[32768];                    // resident k-slice 4, 64 KB
  __shared__ __align__(16) f16 sA[16384];        // stream buf / A-out, 32 KB
  __shared__ __align__(16) f16 sB[16384];        // stream buf / xp-in, 32 KB
  __shared__ __align__(16) f16 apf[8][64][8];    // A-frags, 8 KB
  __shared__ __align__(16) f16 htile[16][264];   // h tile (B-roles), 8.25 KB

  const int tid = threadIdx.x;
  const int lane = tid & 63, w = tid >> 6;
  const int q = lane >> 4, l15 = lane & 15;
  const int role = blockIdx.x >> 6;              // 0:A0 1:B0 2:A1 3:B1
  const int grp = blockIdx.x & 63;
  const int m0 = grp * 16;
  const bool isB = (role & 1) != 0;
  const f16* wb = wrole + (size_t)role * 262144;

  int* fSelf = flags + role * 4096 + grp * 64;
  int* fData = (role > 0) ? flags + (role - 1) * 4096 + grp * 64 : nullptr;
  int* fCred = (role < 3) ? flags + (role + 1) * 4096 + grp * 64 : nullptr;

  // ---- weights: k-slices 0..3 -> 256 VGPRs ----
  f16x8 bfr[16][4];
#pragma unroll
  for (int m = 0; m < 16; m++)
#pragma unroll
    for (int k = 0; k < 4; k++)
      bfr[m][k] = *(const f16x8*)(wb + (((size_t)k * 64 + (w + 4 * m)) * 64 + lane) * 8);
  // ---- k-slice 4 resident in LDS ----
  for (int i = 0; i < 16; i++)
    *(f16x8*)&wres[i * 2048 + tid * 8] = *(const f16x8*)(wb + 4 * 32768 + i * 2048 + tid * 8);

  float bvv[4][4];
  if (isB) {
    const float* bias = (role == 1) ? b0 : b1;
#pragma unroll
    for (int g = 0; g < 4; g++)
#pragma unroll
      for (int mh = 0; mh < 4; mh++)
        bvv[g][mh] = bias[g * 256 + 16 * w + 64 * mh + l15];
  }
  float cst[4][4];
#pragma unroll
  for (int a = 0; a < 4; a++)
#pragma unroll
    for (int r = 0; r < 4; r++) cst[a][r] = 0.f;

  const f16* xpsrc = (role == 1) ? xp0 : xp1;    // B-roles consume
  f16* xpdst = (role == 0) ? xp0 : xp1;          // A-roles produce

  for (int t = 0; t < T_; ++t) {
    // ---- P0: poll producer-data + ring-credit ----
    if (tid == 0) {
      int needD = (role > 0) ? (t + 1) : 0;
      int needC = (role < 3 && t >= R_) ? (t - R_ + 1) : 0;
      int it = 0;
      while ((needD && AL(fData) < needD) || (needC && AL(fCred) < needC)) {
        __builtin_amdgcn_s_sleep(1);
        if (++it > (1 << 24)) break;   // bailout: wrong answer beats a hang
      }
    }
    __syncthreads();

    // ---- P1: stage apf (wave w stages k in {w, w+4}); B: sB <- xp slot;
    //          sA <- streamed W(slice5, half0) ----
    if (isB) {
      if (t > 0) {
#pragma unroll
        for (int kk = 0; kk < 2; kk++) {
          int k = w + 4 * kk;
          *(f16x8*)&apf[k][lane][0] = *(const f16x8*)&htile[l15][k * 32 + q * 8];
        }
      } else {
        const f16x8 zv = {};
#pragma unroll
        for (int kk = 0; kk < 2; kk++) *(f16x8*)&apf[w + 4 * kk][lane][0] = zv;
      }
      const f16* xps = xpsrc + (size_t)grp * (R_ * 16384) + (size_t)(t % R_) * 16384;
      for (int i = 0; i < 8; i++)
        *(f16x8*)&sB[i * 2048 + tid * 8] = aload16(xps + i * 2048 + tid * 8);
    } else if (role == 0) {
#pragma unroll
      for (int kk = 0; kk < 2; kk++) {
        int k = w + 4 * kk;
        *(f16x8*)&apf[k][lane][0] =
            *(const f16x8*)&xA[((size_t)(m0 + l15) * T_ + t) * 256 + k * 32 + q * 8];
      }
    } else {  // A1: x = h0 from ring (B0's agent-scope writes)
      const f16* h0p = h0r + (size_t)grp * (R_ * 4096) + (size_t)(t % R_) * 4096;
#pragma unroll
      for (int kk = 0; kk < 2; kk++) {
        int k = w + 4 * kk;
        *(f16x8*)&apf[k][lane][0] = aload16(&h0p[l15 * 256 + k * 32 + q * 8]);
      }
    }
    {
      const f16* src = wb + 5 * 32768;
      for (int i = 0; i < 8; i++)
        *(f16x8*)&sA[i * 2048 + tid * 8] = *(const f16x8*)(src + i * 2048 + tid * 8);
    }
    __syncthreads();

    // ---- P2: acc init (B: xp from sB) + MFMA k0..3 (regs) + k4 (wres) ----
    f32x4 acc[16];
    if (isB) {
#pragma unroll
      for (int m = 0; m < 16; m++)
#pragma unroll
        for (int r = 0; r < 4; r++)
          acc[m][r] = (float)sB[(q * 4 + r) * 1024 + 16 * (w + 4 * m) + l15];
    } else {
#pragma unroll
      for (int m = 0; m < 16; m++) acc[m] = (f32x4){0.f, 0.f, 0.f, 0.f};
    }
#pragma unroll
    for (int k = 0; k < 4; k++) {
      f16x8 a = *(const f16x8*)&apf[k][lane][0];
#pragma unroll
      for (int m = 0; m < 16; m++)
        acc[m] = __builtin_amdgcn_mfma_f32_16x16x32_f16(a, bfr[m][k], acc[m], 0, 0, 0);
    }
    {
      f16x8 a = *(const f16x8*)&apf[4][lane][0];
#pragma unroll
      for (int m = 0; m < 16; m++) {
        f16x8 bf = *(const f16x8*)&wres[((size_t)(w + 4 * m) * 64 + lane) * 8];
        acc[m] = __builtin_amdgcn_mfma_f32_16x16x32_f16(a, bf, acc[m], 0, 0, 0);
      }
    }
    __syncthreads();   // sB(xp) consumed -> reusable as stream buffer

    // ---- P3..P8: streamed k-slices 5..7 in half-chunks, ping-pong ----
    // stage(next half -> other buf) overlaps MFMA(current half);
    // barrier per phase guarantees buf reuse safety.
#define STAGE_W(S, HH, BUF)                                            \
    { const f16* src_ = wb + (S) * 32768 + (HH) * 16384;               \
      for (int i = 0; i < 8; i++)                                      \
        *(f16x8*)&BUF[i * 2048 + tid * 8] =                            \
            *(const f16x8*)(src_ + i * 2048 + tid * 8); }
#define MFMA_HALF(S, HH, BUF)                                          \
    { f16x8 a_ = *(const f16x8*)&apf[S][lane][0];                      \
      _Pragma("unroll")                                                \
      for (int m = 8 * (HH); m < 8 * (HH) + 8; m++) {                  \
        int ttl = (w + 4 * m) & 31;                                    \
        f16x8 bf_ = *(const f16x8*)&BUF[((size_t)ttl * 64 + lane) * 8];\
        acc[m] = __builtin_amdgcn_mfma_f32_16x16x32_f16(a_, bf_, acc[m], 0, 0, 0); } }

    STAGE_W(5, 1, sB); MFMA_HALF(5, 0, sA);
    __syncthreads();
    STAGE_W(6, 0, sA); MFMA_HALF(5, 1, sB);
    __syncthreads();
    STAGE_W(6, 1, sB); MFMA_HALF(6, 0, sA);
    __syncthreads();
    STAGE_W(7, 0, sA); MFMA_HALF(6, 1, sB);
    __syncthreads();
    STAGE_W(7, 1, sB); MFMA_HALF(7, 0, sA);
    __syncthreads();
    MFMA_HALF(7, 1, sB);

    // ---- P9: outputs to LDS ----
    if (isB) {
      // gates: thread's i/f/g/o for col 16w+64mh+l15 are acc[mh+4g]
#pragma unroll
      for (int mh = 0; mh < 4; mh++)
#pragma unroll
        for (int r = 0; r < 4; r++) {
          float ip = acc[mh][r] + bvv[0][mh];
          float fp = acc[mh + 4][r] + bvv[1][mh];
          float gp = acc[mh + 8][r] + bvv[2][mh];
          float op = acc[mh + 12][r] + bvv[3][mh];
          float cn = sigf(fp) * cst[mh][r] + sigf(ip) * tanh_(gp);
          cst[mh][r] = cn;
          htile[q * 4 + r][16 * w + 64 * mh + l15] = (f16)(sigf(op) * tanh_(cn));
        }
    } else {
      // A: xp output [16][1024] f16 into sA (free: last read was P7)
#pragma unroll
      for (int m = 0; m < 16; m++)
#pragma unroll
        for (int r = 0; r < 4; r++)
          sA[(q * 4 + r) * 1024 + 16 * (w + 4 * m) + l15] = (f16)acc[m][r];
    }
    __syncthreads();

    // ---- P10: global stores (agent-scope), drain, signal ----
    if (role == 1) {          // B0 -> h0 ring
      int row = tid >> 4, c16 = (tid & 15) * 16;
      f16* dst = h0r + (size_t)grp * (R_ * 4096) + (size_t)(t % R_) * 4096 + row * 256 + c16;
      const ull* s_ = (const ull*)&htile[row][c16];
      AS((ull*)dst, s_[0]); AS((ull*)dst + 1, s_[1]);
      AS((ull*)dst + 2, s_[2]); AS((ull*)dst + 3, s_[3]);
    } else if (role == 3) {   // B1 -> hOut (downstream layout [b][t][256])
      int row = tid >> 4, c16 = (tid & 15) * 16;
      f16* dst = hOut + ((size_t)(m0 + row) * T_ + t) * 256 + c16;
      const ull* s_ = (const ull*)&htile[row][c16];
      AS((ull*)dst, s_[0]); AS((ull*)dst + 1, s_[1]);
      AS((ull*)dst + 2, s_[2]); AS((ull*)dst + 3, s_[3]);
    } else {                  // A -> xp ring
      f16* dst = xpdst + (size_t)grp * (R_ * 16384) + (size_t)(t % R_) * 16384;
      for (int i = 0; i < 8; i++) {
        const ull* s_ = (const ull*)&sA[i * 2048 + tid * 8];
        AS((ull*)(dst + i * 2048 + tid * 8), s_[0]);
        AS((ull*)(dst + i * 2048 + tid * 8) + 1, s_[1]);
      }
    }
    __syncthreads();          // drains all stores (vmcnt 0 before barrier)
    if (tid == 0) AS(fSelf, t + 1);
  }
#undef STAGE_W
#undef MFMA_HALF
}

// ---------------- VSN, two-phase ----------------
__global__ __launch_bounds__(256) void vsn_w_kernel(
    const float* __restrict__ x, const float* __restrict__ selw,
    const float* __restrict__ selb, float* __restrict__ wb)
{
  int pos = blockIdx.x * 256 + threadIdx.x;
  const float* xr = x + (size_t)pos * F_;
  float xv[F_];
#pragma unroll
  for (int f = 0; f < F_; f++) xv[f] = xr[f];
  float wv[F_]; float mx = -1e30f;
#pragma unroll
  for (int f = 0; f < F_; f++) {
    float s = selb[f];
#pragma unroll
    for (int f2 = 0; f2 < F_; f2++) s += xv[f2] * selw[f * F_ + f2];
    wv[f] = s; mx = fmaxf(mx, s);
  }
  float se = 0.f;
#pragma unroll
  for (int f = 0; f < F_; f++) { wv[f] = __expf(wv[f] - mx); se += wv[f]; }
  float inv = 1.f / se;
  float* o = wb + (size_t)pos * 18;
#pragma unroll
  for (int f = 0; f < F_; f++) {
    float wt = wv[f] * inv;
    o[f] = wt; o[9 + f] = wt * xv[f];
  }
}

__global__ __launch_bounds__(256) void vsn_h_kernel(
    const float* __restrict__ wb, const float* __restrict__ embw,
    const float* __restrict__ embb, f16* __restrict__ hout)
{
  int j = threadIdx.x;
  float ew[F_], eb[F_];
#pragma unroll
  for (int f = 0; f < F_; f++) { ew[f] = embw[f * H_ + j]; eb[f] = embb[f * H_ + j]; }
  for (int i = 0; i < 128; i++) {
    size_t pos = blockIdx.x + (size_t)i * 1024;
    const float* w = wb + pos * 18;
    float h = 0.f;
#pragma unroll
    for (int f = 0; f < F_; f++) h += w[9 + f] * ew[f] + w[f] * eb[f];
    hout[pos * H_ + j] = (f16)h;
  }
}

// ---------------- attention in h-space ----------------
__global__ __launch_bounds__(256) void qk_kernel(
    const float* __restrict__ qbuf, const float* __restrict__ attn_in_w,
    float* __restrict__ qk)
{
  __shared__ float qs[256];
  int b = blockIdx.x, j = threadIdx.x;
  qs[j] = qbuf[(size_t)b * 256 + j];
  __syncthreads();
#pragma unroll
  for (int h = 0; h < 4; h++) {
    float acc = 0.f;
    for (int d = 0; d < 64; d++)
      acc += qs[h * 64 + d] * attn_in_w[(size_t)(256 + h * 64 + d) * 256 + j];
    qk[((size_t)b * 4 + h) * 256 + j] = acc * 0.125f;
  }
}

__global__ __launch_bounds__(256) void attnpool_kernel(
    const f16* __restrict__ hseq, const float* __restrict__ qk,
    float* __restrict__ hbar)
{
  __shared__ __align__(16) f16 hs[T_][264];
  __shared__ float qks[4][256];
  __shared__ float ps[4][T_];
  int b = blockIdx.x, tid = threadIdx.x;
  for (int i = tid; i < T_ * 32; i += 256) {
    int row = i >> 5, cc = (i & 31) * 8;
    *(f16x8*)&hs[row][cc] = *(const f16x8*)&hseq[((size_t)b * T_ + row) * 256 + cc];
  }
  for (int i = tid; i < 1024; i += 256) qks[i >> 8][i & 255] = qk[(size_t)b * 1024 + i];
  __syncthreads();
  if (tid < T_) {
    float s[4] = {0.f, 0.f, 0.f, 0.f};
    for (int cc = 0; cc < 32; cc++) {
      f16x8 v = *(const f16x8*)&hs[tid][cc * 8];
#pragma unroll
      for (int h = 0; h < 4; h++) {
        float a = 0.f;
#pragma unroll
        for (int j = 0; j < 8; j++) a += qks[h][cc * 8 + j] * (float)v[j];
        s[h] += a;
      }
    }
#pragma unroll
    for (int h = 0; h < 4; h++) ps[h][tid] = s[h];
  }
  __syncthreads();
  {
    int w = tid >> 6, l = tid & 63;
    float a = ps[w][l], bb = ps[w][l + 64];
    float m = fmaxf(a, bb);
#pragma unroll
    for (int o = 32; o > 0; o >>= 1) m = fmaxf(m, __shfl_xor(m, o, 64));
    float e0 = __expf(a - m), e1 = __expf(bb - m);
    float se = e0 + e1;
#pragma unroll
    for (int o = 32; o > 0; o >>= 1) se += __shfl_xor(se, o, 64);
    float inv = 1.f / se;
    ps[w][l] = e0 * inv; ps[w][l + 64] = e1 * inv;
  }
  __syncthreads();
  int j = tid;
  float acc[4] = {0.f, 0.f, 0.f, 0.f};
  for (int t = 0; t < T_; t++) {
    float hv = (float)hs[t][j];
#pragma unroll
    for (int h = 0; h < 4; h++) acc[h] += ps[h][t] * hv;
  }
#pragma unroll
  for (int h = 0; h < 4; h++) hbar[((size_t)b * 4 + h) * 256 + j] = acc[h];
}

__global__ __launch_bounds__(256) void vproj_kernel(
    const float* __restrict__ hbar, const float* __restrict__ attn_in_w,
    const float* __restrict__ attn_in_b, f16* __restrict__ aob)
{
  __shared__ float hb[4][256];
  int b = blockIdx.x, tid = threadIdx.x;
  for (int i = tid; i < 1024; i += 256) hb[i >> 8][i & 255] = hbar[(size_t)b * 1024 + i];
  __syncthreads();
  int d = tid, h = d >> 6;
  const float4* wr = (const float4*)(attn_in_w + (size_t)(512 + d) * 256);
  float acc = 0.f;
  for (int cc = 0; cc < 64; cc++) {
    float4 w4 = wr[cc];
    acc += w4.x * hb[h][cc * 4] + w4.y * hb[h][cc * 4 + 1]
         + w4.z * hb[h][cc * 4 + 2] + w4.w * hb[h][cc * 4 + 3];
  }
  aob[(size_t)b * 256 + d] = (f16)(acc + attn_in_b[512 + d]);
}

// ---------------- GNN prep ----------------
__global__ __launch_bounds__(256) void deg_adjn_kernel(
    const float* __restrict__ adj, const int* __restrict__ sku,
    f16* __restrict__ adjn)
{
  int bp = blockIdx.x;
  int p = sku[bp];
  int tid = threadIdx.x;
  float s = 0.f;
  for (int j = tid; j < P_; j += 256) s += adj[(size_t)p * P_ + j];
  float tot = blk_sum(s);
  float inv = 1.f / fmaxf(tot, 1e-6f);
  for (int b = tid; b < B_; b += 256)
    adjn[(size_t)bp * B_ + b] = (f16)(adj[(size_t)p * P_ + sku[b]] * inv);
}

__global__ void transpose_kernel(const float* __restrict__ hid, f16* __restrict__ hT)
{
  int i = blockIdx.x * 256 + threadIdx.x;
  int b = i >> 8, j = i & 255;
  hT[(size_t)j * B_ + b] = (f16)hid[i];
}

__global__ __launch_bounds__(256) void gelu_ln_kernel(
    const float* __restrict__ pre, const float* __restrict__ lg,
    const float* __restrict__ lb, float* __restrict__ enr,
    f16* __restrict__ hidcat)
{
  int row = blockIdx.x, j = threadIdx.x;
  float xv = pre[row * 256 + j];
  float ge = 0.5f * xv * (1.f + erff(xv * 0.70710678118654752f));
  float mu = blk_sum(ge) * (1.f / 256.f);
  float d = ge - mu;
  float var = blk_sum(d * d) * (1.f / 256.f);
  float y = d * rsqrtf(var + 1e-5f) * lg[j] + lb[j];
  enr[row * 256 + j] = y;
  hidcat[row * 512 + 256 + j] = (f16)y;
}

__global__ __launch_bounds__(256) void final_kernel(
    const float* __restrict__ gpre, const float* __restrict__ enr,
    const float* __restrict__ hid, const float* __restrict__ outw,
    const float* __restrict__ outb, float* __restrict__ out)
{
  int b = blockIdx.x, j = threadIdx.x;
  float gt = sigf(gpre[b * 256 + j]);
  float comb = gt * enr[b * 256 + j] + (1.f - gt) * hid[b * 256 + j];
  float v = comb * outw[j];
  float s = blk_sum(v);
  if (j == 0) out[b] = s + outb[0];
}

// ---------------- one-shot weight prep ----------------
// wrole layout per role (A0=Wih0, B0=Whh0, A1=Wih1, B1=Whh1; each
// [1024 out][256 K]): elem = role*262144 + ((slice*64 + tile)*64 + lane)*8 + j
// W-elem: row = tile*16 + (lane&15); col = slice*32 + (lane>>4)*8 + j
// threads: 1048576 + 3*65536 + 131072 + 2*1024 = 1378304 = 5384 blocks
__global__ void prep_kernel(
    const float* Wih0, const float* Whh0, const float* Wih1, const float* Whh1,
    const float* bih0, const float* bhh0, const float* bih1, const float* bhh1,
    const float* attn_in_w, const float* attn_out_w, const float* gnn_w,
    const float* gate_w,
    f16* wrole, f16* attninf, f16* attnoutf, f16* gnnwf, f16* gatewf,
    float* bias0, float* bias1)
{
  int idx = blockIdx.x * 256 + threadIdx.x;
  if (idx < 1048576) {
    int role = idx >> 18, rem = idx & 262143;
    int j = rem & 7, lane = (rem >> 3) & 63;
    int tile = (rem >> 9) & 63, slice = (rem >> 15) & 7;
    int row = tile * 16 + (lane & 15);
    int col = slice * 32 + ((lane >> 4) << 3) + j;
    const float* src = role == 0 ? Wih0 : role == 1 ? Whh0 : role == 2 ? Wih1 : Whh1;
    wrole[idx] = (f16)src[(size_t)row * 256 + col];
    return;
  }
  int i = idx - 1048576;
  if (i < 65536) { attninf[i] = (f16)attn_in_w[i]; return; }
  i -= 65536;
  if (i < 65536) { attnoutf[i] = (f16)attn_out_w[i]; return; }
  i -= 65536;
  if (i < 65536) { gnnwf[i] = (f16)gnn_w[i]; return; }
  i -= 65536;
  if (i < 131072) { gatewf[i] = (f16)gate_w[i]; return; }
  i -= 131072;
  if (i < 1024) { bias0[i] = bih0[i] + bhh0[i]; return; }
  i -= 1024;
  if (i < 1024) { bias1[i] = bih1[i] + bhh1[i]; return; }
}

// ---------------- launch ----------------
extern "C" void kernel_launch(void* const* d_in, const int* in_sizes, int n_in,
                              void* d_out, int out_size, void* d_ws, size_t ws_size,
                              hipStream_t stream)
{
  const float* x         = (const float*)d_in[0];
  const int*   sku       = (const int*)  d_in[1];
  const float* adj       = (const float*)d_in[2];
  const float* vsn_emb_w = (const float*)d_in[3];
  const float* vsn_emb_b = (const float*)d_in[4];
  const float* vsn_sel_w = (const float*)d_in[5];
  const float* vsn_sel_b = (const float*)d_in[6];
  const float* Wih0 = (const float*)d_in[7];
  const float* Whh0 = (const float*)d_in[8];
  const float* bih0 = (const float*)d_in[9];
  const float* bhh0 = (const float*)d_in[10];
  const float* Wih1 = (const float*)d_in[11];
  const float* Whh1 = (const float*)d_in[12];
  const float* bih1 = (const float*)d_in[13];
  const float* bhh1 = (const float*)d_in[14];
  const float* attn_in_w  = (const float*)d_in[15];
  const float* attn_in_b  = (const float*)d_in[16];
  const float* attn_out_w = (const float*)d_in[17];
  const float* attn_out_b = (const float*)d_in[18];
  const float* gnn_w  = (const float*)d_in[19];
  const float* gnn_b  = (const float*)d_in[20];
  const float* ln_g   = (const float*)d_in[21];
  const float* ln_b   = (const float*)d_in[22];
  const float* gate_w = (const float*)d_in[23];
  const float* gate_b = (const float*)d_in[24];
  const float* out_w  = (const float*)d_in[25];
  const float* out_b  = (const float*)d_in[26];
  (void)in_sizes; (void)n_in; (void)out_size; (void)ws_size;

  const size_t HBYTES = (size_t)B_ * T_ * H_ * 2;   // 64 MiB per h buffer

  char* wsb = (char*)d_ws;
  size_t off = 0;
  auto alloc = [&](size_t bytes) -> void* {
    void* p = wsb + off;
    off += (bytes + 255) & ~(size_t)255;
    return p;
  };
  // persistent
  size_t off_hA = off;
  f16* hA      = (f16*)alloc(HBYTES);   // VSN out = L0 x; dead after LSTM
  f16* hOut    = (f16*)alloc(HBYTES);   // B1 output; downstream input
  f16* wrole   = (f16*)alloc((size_t)4 * 262144 * 2);      // 2 MB
  size_t off_xp0 = off;
  f16* xp0     = (f16*)alloc((size_t)64 * R_ * 16384 * 2); // 16 MB ring
  f16* xp1     = (f16*)alloc((size_t)64 * R_ * 16384 * 2); // 16 MB ring
  f16* h0r     = (f16*)alloc((size_t)64 * R_ * 4096 * 2);  // 4 MB ring
  f16* attninf = (f16*)alloc((size_t)256 * 256 * 2);
  f16* attnoutf= (f16*)alloc((size_t)256 * 256 * 2);
  f16* gnnwf   = (f16*)alloc((size_t)256 * 256 * 2);
  f16* gatewf  = (f16*)alloc((size_t)256 * 512 * 2);
  float* bias0 = (float*)alloc(1024 * 4);
  float* bias1 = (float*)alloc(1024 * 4);
  int* flags   = (int*)alloc(4 * 4096 * 4);                // 64 KB
  // vsn scratch aliases the xp0 ring (dead before the LSTM starts)
  float* wb    = (float*)(wsb + off_xp0);                  // 9.4 MB
  // tail buffers alias the hA region (hA dead after the LSTM)
  off = off_hA;
  float* qbuf  = (float*)alloc((size_t)B_ * 256 * 4);
  float* qk    = (float*)alloc((size_t)B_ * 4 * 256 * 4);
  float* hbar  = (float*)alloc((size_t)B_ * 4 * 256 * 4);
  f16* aob     = (f16*)alloc((size_t)B_ * 256 * 2);
  float* hidden32 = (float*)alloc((size_t)B_ * 256 * 4);
  f16* hidcat  = (f16*)alloc((size_t)B_ * 512 * 2);
  f16* hT      = (f16*)alloc((size_t)256 * B_ * 2);
  f16* adjn    = (f16*)alloc((size_t)B_ * B_ * 2);
  f16* aggf    = (f16*)alloc((size_t)B_ * 256 * 2);
  float* gnnpre= (float*)alloc((size_t)B_ * 256 * 4);
  float* enr32 = (float*)alloc((size_t)B_ * 256 * 4);
  float* gatepre=(float*)alloc((size_t)B_ * 256 * 4);
  // (tail ~17 MB < 64 MiB hA region)

  hipMemsetAsync(flags, 0, 4 * 4096 * 4, stream);

  prep_kernel<<<5384, 256, 0, stream>>>(
      Wih0, Whh0, Wih1, Whh1, bih0, bhh0, bih1, bhh1,
      attn_in_w, attn_out_w, gnn_w, gate_w,
      wrole, attninf, attnoutf, gnnwf, gatewf, bias0, bias1);

  // 1) VSN -> hA (wb lives in the xp0 region; lstm overwrites it after)
  vsn_w_kernel<<<512, 256, 0, stream>>>(x, vsn_sel_w, vsn_sel_b, wb);
  vsn_h_kernel<<<1024, 256, 0, stream>>>(wb, vsn_emb_w, vsn_emb_b, hA);
  // 2) both LSTM layers as a 4-role pipeline, recurrence intra-CU
  lstm4<<<256, 256, 0, stream>>>(hA, hOut, xp0, xp1, h0r, wrole, bias0, bias1, flags);

  // 3) q at t=T-1
  dim3 gS(B_ / 128, 256 / 128);
  gemm_f16<<<gS, 256, 0, stream>>>(hOut + (size_t)(T_ - 1) * 256, T_ * 256, attninf, 256,
                                   attn_in_b, nullptr, 0, qbuf, 256, B_, 256, 256);
  // 4) attention folded into h-space
  qk_kernel<<<B_, 256, 0, stream>>>(qbuf, attn_in_w, qk);
  attnpool_kernel<<<B_, 256, 0, stream>>>(hOut, qk, hbar);
  vproj_kernel<<<B_, 256, 0, stream>>>(hbar, attn_in_w, attn_in_b, aob);
  // 5) hidden
  gemm_f16<<<gS, 256, 0, stream>>>(aob, 256, attnoutf, 256, attn_out_b,
                                   hidcat, 512, hidden32, 256, B_, 256, 256);
  // 6) GNN
  deg_adjn_kernel<<<B_, 256, 0, stream>>>(adj, sku, adjn);
  transpose_kernel<<<B_, 256, 0, stream>>>(hidden32, hT);
  gemm_f16<<<gS, 256, 0, stream>>>(adjn, 1024, hT, 1024, nullptr,
                                   aggf, 256, nullptr, 0, B_, 256, 1024);
  gemm_f16<<<gS, 256, 0, stream>>>(aggf, 256, gnnwf, 256, gnn_b,
                                   nullptr, 0, gnnpre, 256, B_, 256, 256);
  gelu_ln_kernel<<<B_, 256, 0, stream>>>(gnnpre, ln_g, ln_b, enr32, hidcat);
  // 7) gate + output
  gemm_f16<<<gS, 256, 0, stream>>>(hidcat, 512, gatewf, 512, gate_b,
                                   nullptr, 0, gatepre, 256, B_, 256, 512);
  final_kernel<<<B_, 256, 0, stream>>>(gatepre, enr32, hidden32, out_w, out_b, (float*)d_out);
}

// Round 9
// 998.677 us; speedup vs baseline: 3.0617x; 3.0617x over previous
//
#include <hip/hip_runtime.h>
#include <hip/hip_fp16.h>

typedef _Float16 f16;
typedef _Float16 f16x8 __attribute__((ext_vector_type(8)));
typedef _Float16 f16x4 __attribute__((ext_vector_type(4)));
typedef float f32x4 __attribute__((ext_vector_type(4)));

#define B_ 1024
#define T_ 128
#define F_ 9
#define H_ 256
#define P_ 2048

typedef unsigned long long ull;
#define AL(p) __hip_atomic_load((p), __ATOMIC_RELAXED, __HIP_MEMORY_SCOPE_AGENT)
#define AS(p, v) __hip_atomic_store((p), (v), __ATOMIC_RELAXED, __HIP_MEMORY_SCOPE_AGENT)

// ---------------- helpers ----------------
__device__ __forceinline__ float sigf(float x) { return 1.f / (1.f + __expf(-x)); }
__device__ __forceinline__ float tanh_(float x) {
  float a = fminf(fabsf(x), 12.f);
  float e = __expf(2.f * a);
  float r = 1.f - 2.f / (e + 1.f);
  return copysignf(r, x);
}

__device__ __forceinline__ f16x8 aload16(const f16* p) {
  union { ull u[2]; f16x8 v; } r;
  r.u[0] = AL((const ull*)p);
  r.u[1] = AL((const ull*)p + 1);
  return r.v;
}

__device__ __forceinline__ float blk_sum(float v) {
  __shared__ float sh[8];
  int lane = threadIdx.x & 63, w = threadIdx.x >> 6;
  int nw = blockDim.x >> 6;
#pragma unroll
  for (int o = 32; o > 0; o >>= 1) v += __shfl_xor(v, o, 64);
  __syncthreads();
  if (lane == 0) sh[w] = v;
  __syncthreads();
  float t = 0.f;
  for (int i = 0; i < nw; i++) t += sh[i];
  return t;
}

// ---------------- generic fp16 MFMA GEMM (optional transposed f16 out) ----
__global__ __launch_bounds__(256) void gemm_f16(
    const f16* __restrict__ A, int lda,
    const f16* __restrict__ Bt, int ldb,
    const float* __restrict__ bias,
    f16* __restrict__ o16, int ldo16,
    float* __restrict__ o32, int ldo32,
    f16* __restrict__ o16t, int ldt,
    int M, int N, int K)
{
  __shared__ __align__(16) f16 As[128][40];
  __shared__ __align__(16) f16 Bs[128][40];
  const int tid = threadIdx.x;
  const int lane = tid & 63, wave = tid >> 6;
  const int wr = (wave >> 1) * 64, wc = (wave & 1) * 64;
  const int q = lane >> 4, l15 = lane & 15;
  const int bm = blockIdx.x * 128, bn = blockIdx.y * 128;

  f32x4 acc[4][4];
#pragma unroll
  for (int i = 0; i < 4; i++)
#pragma unroll
    for (int j = 0; j < 4; j++) acc[i][j] = (f32x4){0.f, 0.f, 0.f, 0.f};

  for (int k0 = 0; k0 < K; k0 += 32) {
#pragma unroll
    for (int c = 0; c < 2; ++c) {
      int ch = tid + c * 256;
      int row = ch >> 2, kh = (ch & 3) * 8;
      *(f16x8*)&As[row][kh] = *(const f16x8*)&A[(size_t)(bm + row) * lda + k0 + kh];
      *(f16x8*)&Bs[row][kh] = *(const f16x8*)&Bt[(size_t)(bn + row) * ldb + k0 + kh];
    }
    __syncthreads();
    f16x8 af[4], bf[4];
#pragma unroll
    for (int tm = 0; tm < 4; tm++) af[tm] = *(const f16x8*)&As[wr + tm * 16 + l15][q * 8];
#pragma unroll
    for (int tn = 0; tn < 4; tn++) bf[tn] = *(const f16x8*)&Bs[wc + tn * 16 + l15][q * 8];
#pragma unroll
    for (int tm = 0; tm < 4; tm++)
#pragma unroll
      for (int tn = 0; tn < 4; tn++)
        acc[tm][tn] = __builtin_amdgcn_mfma_f32_16x16x32_f16(af[tm], bf[tn], acc[tm][tn], 0, 0, 0);
    __syncthreads();
  }
#pragma unroll
  for (int tm = 0; tm < 4; tm++) {
#pragma unroll
    for (int tn = 0; tn < 4; tn++) {
      int colg = bn + wc + tn * 16 + l15;
      float bv = bias ? bias[colg] : 0.f;
#pragma unroll
      for (int r = 0; r < 4; r++) {
        int rowg = bm + wr + tm * 16 + q * 4 + r;
        float v = acc[tm][tn][r] + bv;
        if (o32) o32[(size_t)rowg * ldo32 + colg] = v;
        if (o16) o16[(size_t)rowg * ldo16 + colg] = (f16)v;
        if (o16t) o16t[(size_t)colg * ldt + rowg] = (f16)v;
      }
    }
  }
}

// ---------------- LSTM v7 (R6, proven 726us): pipeline + flags + own-LDS --
// Both layers pipelined, in place on hio, v2 counter-protocol semantics.
//  (1) own-slice h from LDS htile (saves 25% of h-read atomics).
//  (2) per-slice flag words: producer tid0 atomic-STORES flag[s] = t+2
//      (monotone, own slot, no RMW); consumer polls 4 slices via 2 u64.
//      flag value 1 = x_0 prefetched; t+2 = step t complete (h_t stored+
//      drained AND x_{t+1} prefetch drained).
//  (3) 4 barriers/step.
// Cross-layer: L1 phase-A(t) waits L0 flags >= min(t+3, T+1) -- covers
// h0_t/h0_{t+1} availability, L0's x-consumption of slot t, and L0's
// remote h-reads of slot t before L1's in-place h1_t clobber.
__global__ __launch_bounds__(256, 1) void lstm_pipe(
    f16* __restrict__ hio,
    const f16* __restrict__ wpk0, const f16* __restrict__ wpk1,
    const float* __restrict__ b0, const float* __restrict__ b1,
    int* __restrict__ cnt0, int* __restrict__ cnt1)
{
  __shared__ __align__(16) f16 apf[2][16][64][8];   // A-frags per M-tile, 32 KB
  __shared__ __align__(16) f16 htile[32][64];       // 4 KB
  const int tid = threadIdx.x;
  const int lane = tid & 63, w = tid >> 6;          // wave 0..3
  const int q = lane >> 4, l15 = lane & 15;
  const int layer = blockIdx.x >> 7;                // 0..127 -> L0, 128..255 -> L1
  const int lbid = blockIdx.x & 127;
  const int grp = lbid & 31, s = lbid >> 5;         // 32 groups x 4 col-slices
  const int m0 = grp * 32;
  const f16* wpk = layer ? wpk1 : wpk0;
  const float* bias = layer ? b1 : b0;
  int* myflags = (layer ? cnt1 : cnt0) + grp * 64;  // slots [0..3], 256B apart
  int* xflags  = cnt0 + grp * 64;                   // layer 1 watches layer 0

  // own-slice k-slots: h K-block k in {8..15} covers cols (k-8)*32..; own
  // cols [s*64, s*64+64) are k = 8+2s, 9+2s. Wave w stages k in {8+w, 12+w}:
  const int own0 = ((w >> 1) == s);                 // k = 8+w is own-col
  const int own1 = (((w + 4) >> 1) == s);           // k = 12+w is own-col
  const int offh = (w & 1) * 32;                    // htile col offset for own k

  // ---- weight slice into registers: 64 x f16x8 = 256 regs/lane ----
  f16x8 bf[4][16];
  {
    const f16* wbase = wpk + (((size_t)(s * 4 + w) * 4) * 16) * 512 + lane * 8;
#pragma unroll
    for (int g = 0; g < 4; g++)
#pragma unroll
      for (int k = 0; k < 16; k++)
        bf[g][k] = *(const f16x8*)(wbase + (size_t)(g * 16 + k) * 512);
  }
  float bv[4];
#pragma unroll
  for (int g = 0; g < 4; g++) bv[g] = bias[g * 256 + s * 64 + w * 16 + l15];

  const int srow = lane & 15, scb = lane >> 4;
  size_t rb[2];
  rb[0] = ((size_t)(m0 + srow) * T_) * 256 + scb * 8;
  rb[1] = ((size_t)(m0 + 16 + srow) * T_) * 256 + scb * 8;

  const f16x8 zv = {(f16)0, (f16)0, (f16)0, (f16)0, (f16)0, (f16)0, (f16)0, (f16)0};

  // pre-loop: layer 1 waits for h0_0 (L0 flags >= 2) before reading x_0
  if (layer) {
    if (tid == 0) {
      int it = 0;
      for (;;) {
        ull a = AL((ull*)xflags);
        ull b2 = AL((ull*)xflags + 1);
        if ((int)a >= 2 && (int)(a >> 32) >= 2 &&
            (int)b2 >= 2 && (int)(b2 >> 32) >= 2) break;
        __builtin_amdgcn_s_sleep(1);
        if (++it > (1 << 22)) break;
      }
    }
    __syncthreads();
  }
  f16x8 xr[2][2];
#pragma unroll
  for (int mt = 0; mt < 2; mt++) {
    if (layer) {
      xr[mt][0] = aload16(&hio[rb[mt] + (size_t)w * 32]);
      xr[mt][1] = aload16(&hio[rb[mt] + (size_t)(w + 4) * 32]);
    } else {
      xr[mt][0] = *(const f16x8*)&hio[rb[mt] + (size_t)w * 32];
      xr[mt][1] = *(const f16x8*)&hio[rb[mt] + (size_t)(w + 4) * 32];
    }
  }
  float cst[2][4] = {{0.f, 0.f, 0.f, 0.f}, {0.f, 0.f, 0.f, 0.f}};

  __syncthreads();                   // drains all lanes' x_0 loads
  if (tid == 0) AS(&myflags[s], 1);  // initial signal: x_0 prefetched

  for (int t = 0; t < T_; ++t) {
    // ---- phase A: own group done step t-1; (L1) L0 done step t+1 ----
    if (tid == 0) {
      const int needO = t + 1;
      int needX = 0;
      if (layer) { needX = t + 3; if (needX > T_ + 1) needX = T_ + 1; }
      int it = 0;
      for (;;) {
        ull a = AL((ull*)myflags);
        ull b2 = AL((ull*)myflags + 1);
        bool ok = (int)a >= needO && (int)(a >> 32) >= needO &&
                  (int)b2 >= needO && (int)(b2 >> 32) >= needO;
        if (ok && layer) {
          ull c = AL((ull*)xflags);
          ull d = AL((ull*)xflags + 1);
          ok = (int)c >= needX && (int)(c >> 32) >= needX &&
               (int)d >= needX && (int)(d >> 32) >= needX;
        }
        if (ok) break;
        __builtin_amdgcn_s_sleep(1);
        if (++it > (1 << 22)) break;   // bailout: wrong answer beats a hang
      }
    }
    __syncthreads();                 // S0

    // ---- stage x_t (prefetch regs) + h_{t-1} (own: LDS, remote: MALL) ----
#pragma unroll
    for (int mt = 0; mt < 2; mt++) {
      *(f16x8*)&apf[mt][w][lane][0]     = xr[mt][0];
      *(f16x8*)&apf[mt][w + 4][lane][0] = xr[mt][1];
      f16x8 h0 = zv, h1 = zv;
      if (t > 0) {
        if (own0) h0 = *(const f16x8*)&htile[mt * 16 + srow][offh + scb * 8];
        else      h0 = aload16(&hio[rb[mt] + (size_t)(t - 1) * 256 + (size_t)w * 32]);
        if (own1) h1 = *(const f16x8*)&htile[mt * 16 + srow][offh + scb * 8];
        else      h1 = aload16(&hio[rb[mt] + (size_t)(t - 1) * 256 + (size_t)(w + 4) * 32]);
      }
      *(f16x8*)&apf[mt][8 + w][lane][0]  = h0;
      *(f16x8*)&apf[mt][12 + w][lane][0] = h1;
    }
    __syncthreads();                 // S1: apf staged (htile reads done too)

    // ---- compute: 128 MFMAs (2 M-tiles), B-operands in registers ----
    f32x4 acc[2][4];
#pragma unroll
    for (int mt = 0; mt < 2; mt++)
#pragma unroll
      for (int g = 0; g < 4; g++) acc[mt][g] = (f32x4){0.f, 0.f, 0.f, 0.f};
#pragma unroll
    for (int k = 0; k < 16; k++) {
      f16x8 a0 = *(const f16x8*)&apf[0][k][lane][0];
      f16x8 a1 = *(const f16x8*)&apf[1][k][lane][0];
#pragma unroll
      for (int g = 0; g < 4; g++) {
        acc[0][g] = __builtin_amdgcn_mfma_f32_16x16x32_f16(a0, bf[g][k], acc[0][g], 0, 0, 0);
        acc[1][g] = __builtin_amdgcn_mfma_f32_16x16x32_f16(a1, bf[g][k], acc[1][g], 0, 0, 0);
      }
    }
    // prefetch x_{t+1}; for L1 this is h0_{t+1}, guaranteed by phase-A xflags
    if (t + 1 < T_) {
#pragma unroll
      for (int mt = 0; mt < 2; mt++) {
        if (layer) {
          xr[mt][0] = aload16(&hio[rb[mt] + (size_t)(t + 1) * 256 + (size_t)w * 32]);
          xr[mt][1] = aload16(&hio[rb[mt] + (size_t)(t + 1) * 256 + (size_t)(w + 4) * 32]);
        } else {
          xr[mt][0] = *(const f16x8*)&hio[rb[mt] + (size_t)(t + 1) * 256 + (size_t)w * 32];
          xr[mt][1] = *(const f16x8*)&hio[rb[mt] + (size_t)(t + 1) * 256 + (size_t)(w + 4) * 32];
        }
      }
    }
    // gate math (lane: rows mt*16 + q*4+r, col s*64+w*16+l15)
    f16 hn[2][4];
#pragma unroll
    for (int mt = 0; mt < 2; mt++)
#pragma unroll
      for (int r = 0; r < 4; r++) {
        float ip = acc[mt][0][r] + bv[0];
        float fp = acc[mt][1][r] + bv[1];
        float gp = acc[mt][2][r] + bv[2];
        float op = acc[mt][3][r] + bv[3];
        float cn = sigf(fp) * cst[mt][r] + sigf(ip) * tanh_(gp);
        cst[mt][r] = cn;
        hn[mt][r] = (f16)(sigf(op) * tanh_(cn));
      }
    // htile rewrite safe: stage-readers behind S1; store-readers behind S0/S1.
#pragma unroll
    for (int mt = 0; mt < 2; mt++)
#pragma unroll
      for (int r = 0; r < 4; r++)
        htile[mt * 16 + q * 4 + r][w * 16 + l15] = hn[mt][r];
    __syncthreads();                 // S3: htile ready
    {                                // write h_t over slot t (16B/thread)
      int row = tid >> 3, c8 = (tid & 7) * 8;
      union { ull u[2]; f16x8 v; } uh;
      uh.v = *(const f16x8*)&htile[row][c8];
      ull* dst =
          (ull*)&hio[((size_t)(m0 + row) * T_ + t) * 256 + s * 64 + c8];
      AS(dst, uh.u[0]);
      AS(dst + 1, uh.u[1]);
    }
    __syncthreads();                 // S4: drains h stores + xr prefetch loads
    if (tid == 0) AS(&myflags[s], t + 2);
  }
}

// ---------------- VSN, two-phase ----------------
__global__ __launch_bounds__(256) void vsn_w_kernel(
    const float* __restrict__ x, const float* __restrict__ selw,
    const float* __restrict__ selb, float* __restrict__ wb)
{
  int pos = blockIdx.x * 256 + threadIdx.x;
  const float* xr = x + (size_t)pos * F_;
  float xv[F_];
#pragma unroll
  for (int f = 0; f < F_; f++) xv[f] = xr[f];
  float wv[F_]; float mx = -1e30f;
#pragma unroll
  for (int f = 0; f < F_; f++) {
    float s = selb[f];
#pragma unroll
    for (int f2 = 0; f2 < F_; f2++) s += xv[f2] * selw[f * F_ + f2];
    wv[f] = s; mx = fmaxf(mx, s);
  }
  float se = 0.f;
#pragma unroll
  for (int f = 0; f < F_; f++) { wv[f] = __expf(wv[f] - mx); se += wv[f]; }
  float inv = 1.f / se;
  float* o = wb + (size_t)pos * 18;
#pragma unroll
  for (int f = 0; f < F_; f++) {
    float wt = wv[f] * inv;
    o[f] = wt; o[9 + f] = wt * xv[f];
  }
}

__global__ __launch_bounds__(256) void vsn_h_kernel(
    const float* __restrict__ wb, const float* __restrict__ embw,
    const float* __restrict__ embb, f16* __restrict__ hout)
{
  int j = threadIdx.x;
  float ew[F_], eb[F_];
#pragma unroll
  for (int f = 0; f < F_; f++) { ew[f] = embw[f * H_ + j]; eb[f] = embb[f * H_ + j]; }
  for (int i = 0; i < 128; i++) {
    size_t pos = blockIdx.x + (size_t)i * 1024;
    const float* w = wb + pos * 18;
    float h = 0.f;
#pragma unroll
    for (int f = 0; f < F_; f++) h += w[9 + f] * ew[f] + w[f] * eb[f];
    hout[pos * H_ + j] = (f16)h;
  }
}

// ---------------- fused attention: qk + pool + vproj in one kernel --------
// Phases are the three previously-passing kernels concatenated with LDS
// hand-offs (qks, ps, hb stay in LDS; qk/hbar global buffers eliminated).
__global__ __launch_bounds__(256) void attn_fused_kernel(
    const f16* __restrict__ hseq, const float* __restrict__ qbuf,
    const float* __restrict__ attn_in_w, const float* __restrict__ attn_in_b,
    f16* __restrict__ aob)
{
  __shared__ __align__(16) f16 hs[T_][264];
  __shared__ float qs[256];
  __shared__ float qks[4][256];
  __shared__ float ps[4][T_];
  __shared__ float hb[4][256];
  int b = blockIdx.x, tid = threadIdx.x;
  for (int i = tid; i < T_ * 32; i += 256) {
    int row = i >> 5, cc = (i & 31) * 8;
    *(f16x8*)&hs[row][cc] = *(const f16x8*)&hseq[((size_t)b * T_ + row) * 256 + cc];
  }
  qs[tid] = qbuf[(size_t)b * 256 + tid];
  __syncthreads();
  // ---- qk phase (was qk_kernel): qks[h][j] = 0.125 * q_h . Wk[:,j] ----
  {
    int j = tid;
#pragma unroll
    for (int h = 0; h < 4; h++) {
      float acc = 0.f;
      for (int d = 0; d < 64; d++)
        acc += qs[h * 64 + d] * attn_in_w[(size_t)(256 + h * 64 + d) * 256 + j];
      qks[h][j] = acc * 0.125f;
    }
  }
  __syncthreads();
  // ---- scores phase ----
  if (tid < T_) {
    float s[4] = {0.f, 0.f, 0.f, 0.f};
    for (int cc = 0; cc < 32; cc++) {
      f16x8 v = *(const f16x8*)&hs[tid][cc * 8];
#pragma unroll
      for (int h = 0; h < 4; h++) {
        float a = 0.f;
#pragma unroll
        for (int j = 0; j < 8; j++) a += qks[h][cc * 8 + j] * (float)v[j];
        s[h] += a;
      }
    }
#pragma unroll
    for (int h = 0; h < 4; h++) ps[h][tid] = s[h];
  }
  __syncthreads();
  // ---- softmax over t (wave w handles head w) ----
  {
    int w = tid >> 6, l = tid & 63;
    float a = ps[w][l], bb = ps[w][l + 64];
    float m = fmaxf(a, bb);
#pragma unroll
    for (int o = 32; o > 0; o >>= 1) m = fmaxf(m, __shfl_xor(m, o, 64));
    float e0 = __expf(a - m), e1 = __expf(bb - m);
    float se = e0 + e1;
#pragma unroll
    for (int o = 32; o > 0; o >>= 1) se += __shfl_xor(se, o, 64);
    float inv = 1.f / se;
    ps[w][l] = e0 * inv; ps[w][l + 64] = e1 * inv;
  }
  __syncthreads();
  // ---- pool: hb[h][j] = sum_t p[h][t] * h[t][j] ----
  {
    int j = tid;
    float acc[4] = {0.f, 0.f, 0.f, 0.f};
    for (int t = 0; t < T_; t++) {
      float hv = (float)hs[t][j];
#pragma unroll
      for (int h = 0; h < 4; h++) acc[h] += ps[h][t] * hv;
    }
#pragma unroll
    for (int h = 0; h < 4; h++) hb[h][j] = acc[h];
  }
  __syncthreads();
  // ---- vproj phase (was vproj_kernel) ----
  {
    int d = tid, h = d >> 6;
    const float4* wr = (const float4*)(attn_in_w + (size_t)(512 + d) * 256);
    float acc = 0.f;
    for (int cc = 0; cc < 64; cc++) {
      float4 w4 = wr[cc];
      acc += w4.x * hb[h][cc * 4] + w4.y * hb[h][cc * 4 + 1]
           + w4.z * hb[h][cc * 4 + 2] + w4.w * hb[h][cc * 4 + 3];
    }
    aob[(size_t)b * 256 + d] = (f16)(acc + attn_in_b[512 + d]);
  }
}

// ---------------- GNN prep ----------------
__global__ __launch_bounds__(256) void deg_adjn_kernel(
    const float* __restrict__ adj, const int* __restrict__ sku,
    f16* __restrict__ adjn)
{
  int bp = blockIdx.x;
  int p = sku[bp];
  int tid = threadIdx.x;
  float s = 0.f;
  for (int j = tid; j < P_; j += 256) s += adj[(size_t)p * P_ + j];
  float tot = blk_sum(s);
  float inv = 1.f / fmaxf(tot, 1e-6f);
  for (int b = tid; b < B_; b += 256)
    adjn[(size_t)bp * B_ + b] = (f16)(adj[(size_t)p * P_ + sku[b]] * inv);
}

__global__ __launch_bounds__(256) void gelu_ln_kernel(
    const float* __restrict__ pre, const float* __restrict__ lg,
    const float* __restrict__ lb, float* __restrict__ enr,
    f16* __restrict__ hidcat)
{
  int row = blockIdx.x, j = threadIdx.x;
  float xv = pre[row * 256 + j];
  float ge = 0.5f * xv * (1.f + erff(xv * 0.70710678118654752f));
  float mu = blk_sum(ge) * (1.f / 256.f);
  float d = ge - mu;
  float var = blk_sum(d * d) * (1.f / 256.f);
  float y = d * rsqrtf(var + 1e-5f) * lg[j] + lb[j];
  enr[row * 256 + j] = y;
  hidcat[row * 512 + 256 + j] = (f16)y;
}

__global__ __launch_bounds__(256) void final_kernel(
    const float* __restrict__ gpre, const float* __restrict__ enr,
    const float* __restrict__ hid, const float* __restrict__ outw,
    const float* __restrict__ outb, float* __restrict__ out)
{
  int b = blockIdx.x, j = threadIdx.x;
  float gt = sigf(gpre[b * 256 + j]);
  float comb = gt * enr[b * 256 + j] + (1.f - gt) * hid[b * 256 + j];
  float v = comb * outw[j];
  float s = blk_sum(v);
  if (j == 0) out[b] = s + outb[0];
}

// ---------------- one-shot weight prep (+ flag zeroing) ----------------
// wpk layout: elem = ((((s*4+w)*4+g)*16+k)*64+lane)*8 + j
// row = g*256 + s*64 + w*16 + (lane&15); col = k*32 + (lane>>4)*8 + j
// threads: 524288 + 3*65536 + 131072 + 2*1024 + 4096 = 858112 -> 3353 blocks
__global__ void prep_kernel(
    const float* Wih0, const float* Whh0, const float* Wih1, const float* Whh1,
    const float* bih0, const float* bhh0, const float* bih1, const float* bhh1,
    const float* attn_in_w, const float* attn_out_w, const float* gnn_w,
    const float* gate_w,
    f16* wpk0, f16* wpk1, f16* attninf, f16* attnoutf, f16* gnnwf, f16* gatewf,
    float* bias0, float* bias1, int* flagz)
{
  int idx = blockIdx.x * 256 + threadIdx.x;
  if (idx < 524288) {
    int j = idx & 7, lane = (idx >> 3) & 63, k = (idx >> 9) & 15;
    int g = (idx >> 13) & 3, w = (idx >> 15) & 3, s = (idx >> 17) & 3;
    int row = g * 256 + s * 64 + w * 16 + (lane & 15);
    int col = k * 32 + (lane >> 4) * 8 + j;
    float v0 = col < 256 ? Wih0[(size_t)row * 256 + col] : Whh0[(size_t)row * 256 + col - 256];
    float v1 = col < 256 ? Wih1[(size_t)row * 256 + col] : Whh1[(size_t)row * 256 + col - 256];
    wpk0[idx] = (f16)v0;
    wpk1[idx] = (f16)v1;
    return;
  }
  int i = idx - 524288;
  if (i < 65536) { attninf[i] = (f16)attn_in_w[i]; return; }
  i -= 65536;
  if (i < 65536) { attnoutf[i] = (f16)attn_out_w[i]; return; }
  i -= 65536;
  if (i < 65536) { gnnwf[i] = (f16)gnn_w[i]; return; }
  i -= 65536;
  if (i < 131072) { gatewf[i] = (f16)gate_w[i]; return; }
  i -= 131072;
  if (i < 1024) { bias0[i] = bih0[i] + bhh0[i]; return; }
  i -= 1024;
  if (i < 1024) { bias1[i] = bih1[i] + bhh1[i]; return; }
  i -= 1024;
  if (i < 4096) { flagz[i] = 0; return; }
}

// ---------------- launch ----------------
extern "C" void kernel_launch(void* const* d_in, const int* in_sizes, int n_in,
                              void* d_out, int out_size, void* d_ws, size_t ws_size,
                              hipStream_t stream)
{
  const float* x         = (const float*)d_in[0];
  const int*   sku       = (const int*)  d_in[1];
  const float* adj       = (const float*)d_in[2];
  const float* vsn_emb_w = (const float*)d_in[3];
  const float* vsn_emb_b = (const float*)d_in[4];
  const float* vsn_sel_w = (const float*)d_in[5];
  const float* vsn_sel_b = (const float*)d_in[6];
  const float* Wih0 = (const float*)d_in[7];
  const float* Whh0 = (const float*)d_in[8];
  const float* bih0 = (const float*)d_in[9];
  const float* bhh0 = (const float*)d_in[10];
  const float* Wih1 = (const float*)d_in[11];
  const float* Whh1 = (const float*)d_in[12];
  const float* bih1 = (const float*)d_in[13];
  const float* bhh1 = (const float*)d_in[14];
  const float* attn_in_w  = (const float*)d_in[15];
  const float* attn_in_b  = (const float*)d_in[16];
  const float* attn_out_w = (const float*)d_in[17];
  const float* attn_out_b = (const float*)d_in[18];
  const float* gnn_w  = (const float*)d_in[19];
  const float* gnn_b  = (const float*)d_in[20];
  const float* ln_g   = (const float*)d_in[21];
  const float* ln_b   = (const float*)d_in[22];
  const float* gate_w = (const float*)d_in[23];
  const float* gate_b = (const float*)d_in[24];
  const float* out_w  = (const float*)d_in[25];
  const float* out_b  = (const float*)d_in[26];
  (void)in_sizes; (void)n_in; (void)out_size; (void)ws_size;

  char* wsb = (char*)d_ws;
  size_t off = 0;
  auto alloc = [&](size_t bytes) -> void* {
    void* p = wsb + off;
    off += (bytes + 255) & ~(size_t)255;
    return p;
  };
  // persistent
  f16* hA      = (f16*)alloc((size_t)B_ * T_ * H_ * 2);   // 67 MB, in-place pipeline
  f16* wpk0    = (f16*)alloc((size_t)1024 * 512 * 2);
  f16* wpk1    = (f16*)alloc((size_t)1024 * 512 * 2);
  f16* attninf = (f16*)alloc((size_t)256 * 256 * 2);
  f16* attnoutf= (f16*)alloc((size_t)256 * 256 * 2);
  f16* gnnwf   = (f16*)alloc((size_t)256 * 256 * 2);
  f16* gatewf  = (f16*)alloc((size_t)256 * 512 * 2);
  float* bias0 = (float*)alloc(1024 * 4);
  float* bias1 = (float*)alloc(1024 * 4);
  int* cnt0    = (int*)alloc(32 * 64 * 4);   // per-group flag lines (256B)
  int* cnt1    = (int*)alloc(32 * 64 * 4);   // (cnt0,cnt1 contiguous: 4096 ints)
  size_t off_tail = off;            // region below reused: wb aliases post-LSTM bufs
  float* qbuf  = (float*)alloc((size_t)B_ * 256 * 4);
  f16* aob     = (f16*)alloc((size_t)B_ * 256 * 2);
  float* hidden32 = (float*)alloc((size_t)B_ * 256 * 4);
  f16* hidcat  = (f16*)alloc((size_t)B_ * 512 * 2);
  f16* hT      = (f16*)alloc((size_t)256 * B_ * 2);
  f16* adjn    = (f16*)alloc((size_t)B_ * B_ * 2);
  f16* aggf    = (f16*)alloc((size_t)B_ * 256 * 2);
  float* gnnpre= (float*)alloc((size_t)B_ * 256 * 4);
  float* enr32 = (float*)alloc((size_t)B_ * 256 * 4);
  float* gatepre=(float*)alloc((size_t)B_ * 256 * 4);
  float* wb    = (float*)(wsb + off_tail);  // 9.4 MB, dead before qbuf is written

  // prep also zeroes the flag lines (cnt0..cnt1, 4096 ints) -- runs before lstm
  prep_kernel<<<3353, 256, 0, stream>>>(
      Wih0, Whh0, Wih1, Whh1, bih0, bhh0, bih1, bhh1,
      attn_in_w, attn_out_w, gnn_w, gate_w,
      wpk0, wpk1, attninf, attnoutf, gnnwf, gatewf, bias0, bias1, cnt0);

  // 1) VSN -> hA
  vsn_w_kernel<<<512, 256, 0, stream>>>(x, vsn_sel_w, vsn_sel_b, wb);
  vsn_h_kernel<<<1024, 256, 0, stream>>>(wb, vsn_emb_w, vsn_emb_b, hA);
  // 2) both LSTM layers pipelined in ONE kernel, in place on hA
  lstm_pipe<<<256, 256, 0, stream>>>(hA, wpk0, wpk1, bias0, bias1, cnt0, cnt1);

  // 3) q at t=T-1
  dim3 gS(B_ / 128, 256 / 128);
  gemm_f16<<<gS, 256, 0, stream>>>(hA + (size_t)(T_ - 1) * 256, T_ * 256, attninf, 256,
                                   attn_in_b, nullptr, 0, qbuf, 256, nullptr, 0,
                                   B_, 256, 256);
  // 4) attention folded into h-space (qk + pool + vproj fused)
  attn_fused_kernel<<<B_, 256, 0, stream>>>(hA, qbuf, attn_in_w, attn_in_b, aob);
  // 5) hidden (also emits transposed f16 hT in the epilogue)
  gemm_f16<<<gS, 256, 0, stream>>>(aob, 256, attnoutf, 256, attn_out_b,
                                   hidcat, 512, hidden32, 256, hT, B_,
                                   B_, 256, 256);
  // 6) GNN
  deg_adjn_kernel<<<B_, 256, 0, stream>>>(adj, sku, adjn);
  gemm_f16<<<gS, 256, 0, stream>>>(adjn, 1024, hT, 1024, nullptr,
                                   aggf, 256, nullptr, 0, nullptr, 0,
                                   B_, 256, 1024);
  gemm_f16<<<gS, 256, 0, stream>>>(aggf, 256, gnnwf, 256, gnn_b,
                                   nullptr, 0, gnnpre, 256, nullptr, 0,
                                   B_, 256, 256);
  gelu_ln_kernel<<<B_, 256, 0, stream>>>(gnnpre, ln_g, ln_b, enr32, hidcat);
  // 7) gate + output
  gemm_f16<<<gS, 256, 0, stream>>>(hidcat, 512, gatewf, 512, gate_b,
                                   nullptr, 0, gatepre, 256, nullptr, 0,
                                   B_, 256, 512);
  final_kernel<<<B_, 256, 0, stream>>>(gatepre, enr32, hidden32, out_w, out_b, (float*)d_out);
}

// Round 10
// 951.013 us; speedup vs baseline: 3.2152x; 1.0501x over previous
//
#include <hip/hip_runtime.h>
#include <hip/hip_fp16.h>

typedef _Float16 f16;
typedef _Float16 f16x8 __attribute__((ext_vector_type(8)));
typedef _Float16 f16x4 __attribute__((ext_vector_type(4)));
typedef float f32x4 __attribute__((ext_vector_type(4)));

#define B_ 1024
#define T_ 128
#define F_ 9
#define H_ 256
#define P_ 2048

typedef unsigned long long ull;
#define AL(p) __hip_atomic_load((p), __ATOMIC_RELAXED, __HIP_MEMORY_SCOPE_AGENT)
#define AS(p, v) __hip_atomic_store((p), (v), __ATOMIC_RELAXED, __HIP_MEMORY_SCOPE_AGENT)

// ---------------- helpers ----------------
__device__ __forceinline__ float sigf(float x) { return 1.f / (1.f + __expf(-x)); }
__device__ __forceinline__ float tanh_(float x) {
  float a = fminf(fabsf(x), 12.f);
  float e = __expf(2.f * a);
  float r = 1.f - 2.f / (e + 1.f);
  return copysignf(r, x);
}

__device__ __forceinline__ f16x8 aload16(const f16* p) {
  union { ull u[2]; f16x8 v; } r;
  r.u[0] = AL((const ull*)p);
  r.u[1] = AL((const ull*)p + 1);
  return r.v;
}

__device__ __forceinline__ float blk_sum(float v) {
  __shared__ float sh[8];
  int lane = threadIdx.x & 63, w = threadIdx.x >> 6;
  int nw = blockDim.x >> 6;
#pragma unroll
  for (int o = 32; o > 0; o >>= 1) v += __shfl_xor(v, o, 64);
  __syncthreads();
  if (lane == 0) sh[w] = v;
  __syncthreads();
  float t = 0.f;
  for (int i = 0; i < nw; i++) t += sh[i];
  return t;
}

// ---------------- 64x64-tile fp16 MFMA GEMM (tail shapes) -----------------
// Same fragment layout / epilogue semantics as the proven 128-tile kernel,
// quartered tile so grid = (M/64, N/64): 64 blocks for M=1024,N=256 (vs 16)
// -> 4x the CUs on these tiny parallelism-starved GEMMs.
__global__ __launch_bounds__(256) void gemm64(
    const f16* __restrict__ A, int lda,
    const f16* __restrict__ Bt, int ldb,
    const float* __restrict__ bias,
    f16* __restrict__ o16, int ldo16,
    float* __restrict__ o32, int ldo32,
    f16* __restrict__ o16t, int ldt,
    int M, int N, int K)
{
  __shared__ __align__(16) f16 As[64][40];
  __shared__ __align__(16) f16 Bs[64][40];
  const int tid = threadIdx.x;
  const int lane = tid & 63, wave = tid >> 6;
  const int q = lane >> 4, l15 = lane & 15;
  const int bm = blockIdx.x * 64, bn = blockIdx.y * 64;

  f32x4 acc[4];
#pragma unroll
  for (int tn = 0; tn < 4; tn++) acc[tn] = (f32x4){0.f, 0.f, 0.f, 0.f};

  for (int k0 = 0; k0 < K; k0 += 32) {
    int row = tid >> 2, kh = (tid & 3) * 8;
    *(f16x8*)&As[row][kh] = *(const f16x8*)&A[(size_t)(bm + row) * lda + k0 + kh];
    *(f16x8*)&Bs[row][kh] = *(const f16x8*)&Bt[(size_t)(bn + row) * ldb + k0 + kh];
    __syncthreads();
    f16x8 af = *(const f16x8*)&As[wave * 16 + l15][q * 8];
#pragma unroll
    for (int tn = 0; tn < 4; tn++) {
      f16x8 bf = *(const f16x8*)&Bs[tn * 16 + l15][q * 8];
      acc[tn] = __builtin_amdgcn_mfma_f32_16x16x32_f16(af, bf, acc[tn], 0, 0, 0);
    }
    __syncthreads();
  }
#pragma unroll
  for (int tn = 0; tn < 4; tn++) {
    int colg = bn + tn * 16 + l15;
    float bv = bias ? bias[colg] : 0.f;
#pragma unroll
    for (int r = 0; r < 4; r++) {
      int rowg = bm + wave * 16 + q * 4 + r;
      float v = acc[tn][r] + bv;
      if (o32) o32[(size_t)rowg * ldo32 + colg] = v;
      if (o16) o16[(size_t)rowg * ldo16 + colg] = (f16)v;
      if (o16t) o16t[(size_t)colg * ldt + rowg] = (f16)v;
    }
  }
}

// ---------------- LSTM v7 (R6, proven 726us): pipeline + flags + own-LDS --
// Both layers pipelined, in place on hio, v2 counter-protocol semantics.
//  (1) own-slice h from LDS htile (saves 25% of h-read atomics).
//  (2) per-slice flag words: producer tid0 atomic-STORES flag[s] = t+2
//      (monotone, own slot, no RMW); consumer polls 4 slices via 2 u64.
//      flag value 1 = x_0 prefetched; t+2 = step t complete (h_t stored+
//      drained AND x_{t+1} prefetch drained).
//  (3) 4 barriers/step.
// Cross-layer: L1 phase-A(t) waits L0 flags >= min(t+3, T+1) -- covers
// h0_t/h0_{t+1} availability, L0's x-consumption of slot t, and L0's
// remote h-reads of slot t before L1's in-place h1_t clobber.
// NOTE (R9 analysis): weight state per col-slice is 256 KB regardless of
// row count -> two protocol blocks per CU would need the whole 512-KB
// register file for weights alone. This 1-block/CU 2-layer pipeline is
// register-optimal; six protocol variants bracket its floor at 726-832us.
__global__ __launch_bounds__(256, 1) void lstm_pipe(
    f16* __restrict__ hio,
    const f16* __restrict__ wpk0, const f16* __restrict__ wpk1,
    const float* __restrict__ b0, const float* __restrict__ b1,
    int* __restrict__ cnt0, int* __restrict__ cnt1)
{
  __shared__ __align__(16) f16 apf[2][16][64][8];   // A-frags per M-tile, 32 KB
  __shared__ __align__(16) f16 htile[32][64];       // 4 KB
  const int tid = threadIdx.x;
  const int lane = tid & 63, w = tid >> 6;          // wave 0..3
  const int q = lane >> 4, l15 = lane & 15;
  const int layer = blockIdx.x >> 7;                // 0..127 -> L0, 128..255 -> L1
  const int lbid = blockIdx.x & 127;
  const int grp = lbid & 31, s = lbid >> 5;         // 32 groups x 4 col-slices
  const int m0 = grp * 32;
  const f16* wpk = layer ? wpk1 : wpk0;
  const float* bias = layer ? b1 : b0;
  int* myflags = (layer ? cnt1 : cnt0) + grp * 64;  // slots [0..3], 256B apart
  int* xflags  = cnt0 + grp * 64;                   // layer 1 watches layer 0

  const int own0 = ((w >> 1) == s);                 // k = 8+w is own-col
  const int own1 = (((w + 4) >> 1) == s);           // k = 12+w is own-col
  const int offh = (w & 1) * 32;                    // htile col offset for own k

  // ---- weight slice into registers: 64 x f16x8 = 256 regs/lane ----
  f16x8 bf[4][16];
  {
    const f16* wbase = wpk + (((size_t)(s * 4 + w) * 4) * 16) * 512 + lane * 8;
#pragma unroll
    for (int g = 0; g < 4; g++)
#pragma unroll
      for (int k = 0; k < 16; k++)
        bf[g][k] = *(const f16x8*)(wbase + (size_t)(g * 16 + k) * 512);
  }
  float bv[4];
#pragma unroll
  for (int g = 0; g < 4; g++) bv[g] = bias[g * 256 + s * 64 + w * 16 + l15];

  const int srow = lane & 15, scb = lane >> 4;
  size_t rb[2];
  rb[0] = ((size_t)(m0 + srow) * T_) * 256 + scb * 8;
  rb[1] = ((size_t)(m0 + 16 + srow) * T_) * 256 + scb * 8;

  const f16x8 zv = {(f16)0, (f16)0, (f16)0, (f16)0, (f16)0, (f16)0, (f16)0, (f16)0};

  // pre-loop: layer 1 waits for h0_0 (L0 flags >= 2) before reading x_0
  if (layer) {
    if (tid == 0) {
      int it = 0;
      for (;;) {
        ull a = AL((ull*)xflags);
        ull b2 = AL((ull*)xflags + 1);
        if ((int)a >= 2 && (int)(a >> 32) >= 2 &&
            (int)b2 >= 2 && (int)(b2 >> 32) >= 2) break;
        __builtin_amdgcn_s_sleep(1);
        if (++it > (1 << 22)) break;
      }
    }
    __syncthreads();
  }
  f16x8 xr[2][2];
#pragma unroll
  for (int mt = 0; mt < 2; mt++) {
    if (layer) {
      xr[mt][0] = aload16(&hio[rb[mt] + (size_t)w * 32]);
      xr[mt][1] = aload16(&hio[rb[mt] + (size_t)(w + 4) * 32]);
    } else {
      xr[mt][0] = *(const f16x8*)&hio[rb[mt] + (size_t)w * 32];
      xr[mt][1] = *(const f16x8*)&hio[rb[mt] + (size_t)(w + 4) * 32];
    }
  }
  float cst[2][4] = {{0.f, 0.f, 0.f, 0.f}, {0.f, 0.f, 0.f, 0.f}};

  __syncthreads();                   // drains all lanes' x_0 loads
  if (tid == 0) AS(&myflags[s], 1);  // initial signal: x_0 prefetched

  for (int t = 0; t < T_; ++t) {
    // ---- phase A: own group done step t-1; (L1) L0 done step t+1 ----
    if (tid == 0) {
      const int needO = t + 1;
      int needX = 0;
      if (layer) { needX = t + 3; if (needX > T_ + 1) needX = T_ + 1; }
      int it = 0;
      for (;;) {
        ull a = AL((ull*)myflags);
        ull b2 = AL((ull*)myflags + 1);
        bool ok = (int)a >= needO && (int)(a >> 32) >= needO &&
                  (int)b2 >= needO && (int)(b2 >> 32) >= needO;
        if (ok && layer) {
          ull c = AL((ull*)xflags);
          ull d = AL((ull*)xflags + 1);
          ok = (int)c >= needX && (int)(c >> 32) >= needX &&
               (int)d >= needX && (int)(d >> 32) >= needX;
        }
        if (ok) break;
        __builtin_amdgcn_s_sleep(1);
        if (++it > (1 << 22)) break;   // bailout: wrong answer beats a hang
      }
    }
    __syncthreads();                 // S0

    // ---- stage x_t (prefetch regs) + h_{t-1} (own: LDS, remote: MALL) ----
#pragma unroll
    for (int mt = 0; mt < 2; mt++) {
      *(f16x8*)&apf[mt][w][lane][0]     = xr[mt][0];
      *(f16x8*)&apf[mt][w + 4][lane][0] = xr[mt][1];
      f16x8 h0 = zv, h1 = zv;
      if (t > 0) {
        if (own0) h0 = *(const f16x8*)&htile[mt * 16 + srow][offh + scb * 8];
        else      h0 = aload16(&hio[rb[mt] + (size_t)(t - 1) * 256 + (size_t)w * 32]);
        if (own1) h1 = *(const f16x8*)&htile[mt * 16 + srow][offh + scb * 8];
        else      h1 = aload16(&hio[rb[mt] + (size_t)(t - 1) * 256 + (size_t)(w + 4) * 32]);
      }
      *(f16x8*)&apf[mt][8 + w][lane][0]  = h0;
      *(f16x8*)&apf[mt][12 + w][lane][0] = h1;
    }
    __syncthreads();                 // S1: apf staged (htile reads done too)

    // ---- compute: 128 MFMAs (2 M-tiles), B-operands in registers ----
    f32x4 acc[2][4];
#pragma unroll
    for (int mt = 0; mt < 2; mt++)
#pragma unroll
      for (int g = 0; g < 4; g++) acc[mt][g] = (f32x4){0.f, 0.f, 0.f, 0.f};
#pragma unroll
    for (int k = 0; k < 16; k++) {
      f16x8 a0 = *(const f16x8*)&apf[0][k][lane][0];
      f16x8 a1 = *(const f16x8*)&apf[1][k][lane][0];
#pragma unroll
      for (int g = 0; g < 4; g++) {
        acc[0][g] = __builtin_amdgcn_mfma_f32_16x16x32_f16(a0, bf[g][k], acc[0][g], 0, 0, 0);
        acc[1][g] = __builtin_amdgcn_mfma_f32_16x16x32_f16(a1, bf[g][k], acc[1][g], 0, 0, 0);
      }
    }
    // prefetch x_{t+1}; for L1 this is h0_{t+1}, guaranteed by phase-A xflags
    if (t + 1 < T_) {
#pragma unroll
      for (int mt = 0; mt < 2; mt++) {
        if (layer) {
          xr[mt][0] = aload16(&hio[rb[mt] + (size_t)(t + 1) * 256 + (size_t)w * 32]);
          xr[mt][1] = aload16(&hio[rb[mt] + (size_t)(t + 1) * 256 + (size_t)(w + 4) * 32]);
        } else {
          xr[mt][0] = *(const f16x8*)&hio[rb[mt] + (size_t)(t + 1) * 256 + (size_t)w * 32];
          xr[mt][1] = *(const f16x8*)&hio[rb[mt] + (size_t)(t + 1) * 256 + (size_t)(w + 4) * 32];
        }
      }
    }
    // gate math (lane: rows mt*16 + q*4+r, col s*64+w*16+l15)
    f16 hn[2][4];
#pragma unroll
    for (int mt = 0; mt < 2; mt++)
#pragma unroll
      for (int r = 0; r < 4; r++) {
        float ip = acc[mt][0][r] + bv[0];
        float fp = acc[mt][1][r] + bv[1];
        float gp = acc[mt][2][r] + bv[2];
        float op = acc[mt][3][r] + bv[3];
        float cn = sigf(fp) * cst[mt][r] + sigf(ip) * tanh_(gp);
        cst[mt][r] = cn;
        hn[mt][r] = (f16)(sigf(op) * tanh_(cn));
      }
    // htile rewrite safe: stage-readers behind S1; store-readers behind S0/S1.
#pragma unroll
    for (int mt = 0; mt < 2; mt++)
#pragma unroll
      for (int r = 0; r < 4; r++)
        htile[mt * 16 + q * 4 + r][w * 16 + l15] = hn[mt][r];
    __syncthreads();                 // S3: htile ready
    {                                // write h_t over slot t (16B/thread)
      int row = tid >> 3, c8 = (tid & 7) * 8;
      union { ull u[2]; f16x8 v; } uh;
      uh.v = *(const f16x8*)&htile[row][c8];
      ull* dst =
          (ull*)&hio[((size_t)(m0 + row) * T_ + t) * 256 + s * 64 + c8];
      AS(dst, uh.u[0]);
      AS(dst + 1, uh.u[1]);
    }
    __syncthreads();                 // S4: drains h stores + xr prefetch loads
    if (tid == 0) AS(&myflags[s], t + 2);
  }
}

// ---------------- VSN fused: weights + embedding dot in one kernel --------
// Block b owns batch-row b (positions b*128..b*128+127 = all t).
// Phase 1: threads 0..127 compute per-position softmax weights into LDS.
// Phase 2: thread j computes h[., j] for all 128 positions from LDS.
// Removes the 9.4-MB wb global round-trip and one launch.
__global__ __launch_bounds__(256) void vsn_fused_kernel(
    const float* __restrict__ x, const float* __restrict__ selw,
    const float* __restrict__ selb, const float* __restrict__ embw,
    const float* __restrict__ embb, f16* __restrict__ hout)
{
  __shared__ float wbs[128][18];
  int b = blockIdx.x, tid = threadIdx.x;
  if (tid < 128) {
    size_t pos = (size_t)b * 128 + tid;
    const float* xr = x + pos * F_;
    float xv[F_];
#pragma unroll
    for (int f = 0; f < F_; f++) xv[f] = xr[f];
    float wv[F_]; float mx = -1e30f;
#pragma unroll
    for (int f = 0; f < F_; f++) {
      float s = selb[f];
#pragma unroll
      for (int f2 = 0; f2 < F_; f2++) s += xv[f2] * selw[f * F_ + f2];
      wv[f] = s; mx = fmaxf(mx, s);
    }
    float se = 0.f;
#pragma unroll
    for (int f = 0; f < F_; f++) { wv[f] = __expf(wv[f] - mx); se += wv[f]; }
    float inv = 1.f / se;
#pragma unroll
    for (int f = 0; f < F_; f++) {
      float wt = wv[f] * inv;
      wbs[tid][f] = wt; wbs[tid][9 + f] = wt * xv[f];
    }
  }
  __syncthreads();
  int j = tid;
  float ew[F_], eb[F_];
#pragma unroll
  for (int f = 0; f < F_; f++) { ew[f] = embw[f * H_ + j]; eb[f] = embb[f * H_ + j]; }
  for (int i = 0; i < 128; i++) {
    float h = 0.f;
#pragma unroll
    for (int f = 0; f < F_; f++) h += wbs[i][9 + f] * ew[f] + wbs[i][f] * eb[f];
    hout[((size_t)b * 128 + i) * H_ + j] = (f16)h;
  }
}

// ---------------- fused attention: qk + pool + vproj in one kernel --------
__global__ __launch_bounds__(256) void attn_fused_kernel(
    const f16* __restrict__ hseq, const float* __restrict__ qbuf,
    const float* __restrict__ attn_in_w, const float* __restrict__ attn_in_b,
    f16* __restrict__ aob)
{
  __shared__ __align__(16) f16 hs[T_][264];
  __shared__ float qs[256];
  __shared__ float qks[4][256];
  __shared__ float ps[4][T_];
  __shared__ float hb[4][256];
  int b = blockIdx.x, tid = threadIdx.x;
  for (int i = tid; i < T_ * 32; i += 256) {
    int row = i >> 5, cc = (i & 31) * 8;
    *(f16x8*)&hs[row][cc] = *(const f16x8*)&hseq[((size_t)b * T_ + row) * 256 + cc];
  }
  qs[tid] = qbuf[(size_t)b * 256 + tid];
  __syncthreads();
  // ---- qk phase ----
  {
    int j = tid;
#pragma unroll
    for (int h = 0; h < 4; h++) {
      float acc = 0.f;
      for (int d = 0; d < 64; d++)
        acc += qs[h * 64 + d] * attn_in_w[(size_t)(256 + h * 64 + d) * 256 + j];
      qks[h][j] = acc * 0.125f;
    }
  }
  __syncthreads();
  // ---- scores phase ----
  if (tid < T_) {
    float s[4] = {0.f, 0.f, 0.f, 0.f};
    for (int cc = 0; cc < 32; cc++) {
      f16x8 v = *(const f16x8*)&hs[tid][cc * 8];
#pragma unroll
      for (int h = 0; h < 4; h++) {
        float a = 0.f;
#pragma unroll
        for (int j = 0; j < 8; j++) a += qks[h][cc * 8 + j] * (float)v[j];
        s[h] += a;
      }
    }
#pragma unroll
    for (int h = 0; h < 4; h++) ps[h][tid] = s[h];
  }
  __syncthreads();
  // ---- softmax over t (wave w handles head w) ----
  {
    int w = tid >> 6, l = tid & 63;
    float a = ps[w][l], bb = ps[w][l + 64];
    float m = fmaxf(a, bb);
#pragma unroll
    for (int o = 32; o > 0; o >>= 1) m = fmaxf(m, __shfl_xor(m, o, 64));
    float e0 = __expf(a - m), e1 = __expf(bb - m);
    float se = e0 + e1;
#pragma unroll
    for (int o = 32; o > 0; o >>= 1) se += __shfl_xor(se, o, 64);
    float inv = 1.f / se;
    ps[w][l] = e0 * inv; ps[w][l + 64] = e1 * inv;
  }
  __syncthreads();
  // ---- pool ----
  {
    int j = tid;
    float acc[4] = {0.f, 0.f, 0.f, 0.f};
    for (int t = 0; t < T_; t++) {
      float hv = (float)hs[t][j];
#pragma unroll
      for (int h = 0; h < 4; h++) acc[h] += ps[h][t] * hv;
    }
#pragma unroll
    for (int h = 0; h < 4; h++) hb[h][j] = acc[h];
  }
  __syncthreads();
  // ---- vproj phase ----
  {
    int d = tid, h = d >> 6;
    const float4* wr = (const float4*)(attn_in_w + (size_t)(512 + d) * 256);
    float acc = 0.f;
    for (int cc = 0; cc < 64; cc++) {
      float4 w4 = wr[cc];
      acc += w4.x * hb[h][cc * 4] + w4.y * hb[h][cc * 4 + 1]
           + w4.z * hb[h][cc * 4 + 2] + w4.w * hb[h][cc * 4 + 3];
    }
    aob[(size_t)b * 256 + d] = (f16)(acc + attn_in_b[512 + d]);
  }
}

// ---------------- GNN / epilogue kernels ----------------
__global__ __launch_bounds__(256) void gelu_ln_kernel(
    const float* __restrict__ pre, const float* __restrict__ lg,
    const float* __restrict__ lb, float* __restrict__ enr,
    f16* __restrict__ hidcat)
{
  int row = blockIdx.x, j = threadIdx.x;
  float xv = pre[row * 256 + j];
  float ge = 0.5f * xv * (1.f + erff(xv * 0.70710678118654752f));
  float mu = blk_sum(ge) * (1.f / 256.f);
  float d = ge - mu;
  float var = blk_sum(d * d) * (1.f / 256.f);
  float y = d * rsqrtf(var + 1e-5f) * lg[j] + lb[j];
  enr[row * 256 + j] = y;
  hidcat[row * 512 + 256 + j] = (f16)y;
}

__global__ __launch_bounds__(256) void final_kernel(
    const float* __restrict__ gpre, const float* __restrict__ enr,
    const float* __restrict__ hid, const float* __restrict__ outw,
    const float* __restrict__ outb, float* __restrict__ out)
{
  int b = blockIdx.x, j = threadIdx.x;
  float gt = sigf(gpre[b * 256 + j]);
  float comb = gt * enr[b * 256 + j] + (1.f - gt) * hid[b * 256 + j];
  float v = comb * outw[j];
  float s = blk_sum(v);
  if (j == 0) out[b] = s + outb[0];
}

// ---------------- one-shot weight prep (+ flags + deg/adjn) ----------------
// Blocks 0..3352: weight packing / conversions / flag zeroing (as before).
// Blocks 3353..4376: deg_adjn work (bp = blockIdx - 3353) -- independent of
// all prep outputs (reads adj/sku only), merged here to save a launch.
__global__ void prep_kernel(
    const float* Wih0, const float* Whh0, const float* Wih1, const float* Whh1,
    const float* bih0, const float* bhh0, const float* bih1, const float* bhh1,
    const float* attn_in_w, const float* attn_out_w, const float* gnn_w,
    const float* gate_w, const float* adj, const int* sku,
    f16* wpk0, f16* wpk1, f16* attninf, f16* attnoutf, f16* gnnwf, f16* gatewf,
    float* bias0, float* bias1, int* flagz, f16* adjn)
{
  if (blockIdx.x >= 3353) {
    int bp = blockIdx.x - 3353;
    int p = sku[bp];
    int tid = threadIdx.x;
    float s = 0.f;
    for (int j = tid; j < P_; j += 256) s += adj[(size_t)p * P_ + j];
    float tot = blk_sum(s);
    float inv = 1.f / fmaxf(tot, 1e-6f);
    for (int b = tid; b < B_; b += 256)
      adjn[(size_t)bp * B_ + b] = (f16)(adj[(size_t)p * P_ + sku[b]] * inv);
    return;
  }
  int idx = blockIdx.x * 256 + threadIdx.x;
  if (idx < 524288) {
    int j = idx & 7, lane = (idx >> 3) & 63, k = (idx >> 9) & 15;
    int g = (idx >> 13) & 3, w = (idx >> 15) & 3, s = (idx >> 17) & 3;
    int row = g * 256 + s * 64 + w * 16 + (lane & 15);
    int col = k * 32 + (lane >> 4) * 8 + j;
    float v0 = col < 256 ? Wih0[(size_t)row * 256 + col] : Whh0[(size_t)row * 256 + col - 256];
    float v1 = col < 256 ? Wih1[(size_t)row * 256 + col] : Whh1[(size_t)row * 256 + col - 256];
    wpk0[idx] = (f16)v0;
    wpk1[idx] = (f16)v1;
    return;
  }
  int i = idx - 524288;
  if (i < 65536) { attninf[i] = (f16)attn_in_w[i]; return; }
  i -= 65536;
  if (i < 65536) { attnoutf[i] = (f16)attn_out_w[i]; return; }
  i -= 65536;
  if (i < 65536) { gnnwf[i] = (f16)gnn_w[i]; return; }
  i -= 65536;
  if (i < 131072) { gatewf[i] = (f16)gate_w[i]; return; }
  i -= 131072;
  if (i < 1024) { bias0[i] = bih0[i] + bhh0[i]; return; }
  i -= 1024;
  if (i < 1024) { bias1[i] = bih1[i] + bhh1[i]; return; }
  i -= 1024;
  if (i < 4096) { flagz[i] = 0; return; }
}

// ---------------- launch ----------------
extern "C" void kernel_launch(void* const* d_in, const int* in_sizes, int n_in,
                              void* d_out, int out_size, void* d_ws, size_t ws_size,
                              hipStream_t stream)
{
  const float* x         = (const float*)d_in[0];
  const int*   sku       = (const int*)  d_in[1];
  const float* adj       = (const float*)d_in[2];
  const float* vsn_emb_w = (const float*)d_in[3];
  const float* vsn_emb_b = (const float*)d_in[4];
  const float* vsn_sel_w = (const float*)d_in[5];
  const float* vsn_sel_b = (const float*)d_in[6];
  const float* Wih0 = (const float*)d_in[7];
  const float* Whh0 = (const float*)d_in[8];
  const float* bih0 = (const float*)d_in[9];
  const float* bhh0 = (const float*)d_in[10];
  const float* Wih1 = (const float*)d_in[11];
  const float* Whh1 = (const float*)d_in[12];
  const float* bih1 = (const float*)d_in[13];
  const float* bhh1 = (const float*)d_in[14];
  const float* attn_in_w  = (const float*)d_in[15];
  const float* attn_in_b  = (const float*)d_in[16];
  const float* attn_out_w = (const float*)d_in[17];
  const float* attn_out_b = (const float*)d_in[18];
  const float* gnn_w  = (const float*)d_in[19];
  const float* gnn_b  = (const float*)d_in[20];
  const float* ln_g   = (const float*)d_in[21];
  const float* ln_b   = (const float*)d_in[22];
  const float* gate_w = (const float*)d_in[23];
  const float* gate_b = (const float*)d_in[24];
  const float* out_w  = (const float*)d_in[25];
  const float* out_b  = (const float*)d_in[26];
  (void)in_sizes; (void)n_in; (void)out_size; (void)ws_size;

  char* wsb = (char*)d_ws;
  size_t off = 0;
  auto alloc = [&](size_t bytes) -> void* {
    void* p = wsb + off;
    off += (bytes + 255) & ~(size_t)255;
    return p;
  };
  // persistent
  f16* hA      = (f16*)alloc((size_t)B_ * T_ * H_ * 2);   // 67 MB, in-place pipeline
  f16* wpk0    = (f16*)alloc((size_t)1024 * 512 * 2);
  f16* wpk1    = (f16*)alloc((size_t)1024 * 512 * 2);
  f16* attninf = (f16*)alloc((size_t)256 * 256 * 2);
  f16* attnoutf= (f16*)alloc((size_t)256 * 256 * 2);
  f16* gnnwf   = (f16*)alloc((size_t)256 * 256 * 2);
  f16* gatewf  = (f16*)alloc((size_t)256 * 512 * 2);
  float* bias0 = (float*)alloc(1024 * 4);
  float* bias1 = (float*)alloc(1024 * 4);
  int* cnt0    = (int*)alloc(32 * 64 * 4);   // per-group flag lines (256B)
  int* cnt1    = (int*)alloc(32 * 64 * 4);   // (cnt0,cnt1 contiguous: 4096 ints)
  f16* adjn    = (f16*)alloc((size_t)B_ * B_ * 2);
  float* qbuf  = (float*)alloc((size_t)B_ * 256 * 4);
  f16* aob     = (f16*)alloc((size_t)B_ * 256 * 2);
  float* hidden32 = (float*)alloc((size_t)B_ * 256 * 4);
  f16* hidcat  = (f16*)alloc((size_t)B_ * 512 * 2);
  f16* hT      = (f16*)alloc((size_t)256 * B_ * 2);
  f16* aggf    = (f16*)alloc((size_t)B_ * 256 * 2);
  float* gnnpre= (float*)alloc((size_t)B_ * 256 * 4);
  float* enr32 = (float*)alloc((size_t)B_ * 256 * 4);
  float* gatepre=(float*)alloc((size_t)B_ * 256 * 4);

  // prep: weight packing + flag zeroing + deg/adjn (extra 1024 blocks)
  prep_kernel<<<4377, 256, 0, stream>>>(
      Wih0, Whh0, Wih1, Whh1, bih0, bhh0, bih1, bhh1,
      attn_in_w, attn_out_w, gnn_w, gate_w, adj, sku,
      wpk0, wpk1, attninf, attnoutf, gnnwf, gatewf, bias0, bias1, cnt0, adjn);

  // 1) VSN -> hA (fused single kernel)
  vsn_fused_kernel<<<B_, 256, 0, stream>>>(x, vsn_sel_w, vsn_sel_b,
                                           vsn_emb_w, vsn_emb_b, hA);
  // 2) both LSTM layers pipelined in ONE kernel, in place on hA
  lstm_pipe<<<256, 256, 0, stream>>>(hA, wpk0, wpk1, bias0, bias1, cnt0, cnt1);

  // 3) q at t=T-1  (64x64 tiles: 64 blocks)
  dim3 g64(B_ / 64, 256 / 64);
  gemm64<<<g64, 256, 0, stream>>>(hA + (size_t)(T_ - 1) * 256, T_ * 256, attninf, 256,
                                  attn_in_b, nullptr, 0, qbuf, 256, nullptr, 0,
                                  B_, 256, 256);
  // 4) attention folded into h-space (qk + pool + vproj fused)
  attn_fused_kernel<<<B_, 256, 0, stream>>>(hA, qbuf, attn_in_w, attn_in_b, aob);
  // 5) hidden (also emits transposed f16 hT in the epilogue)
  gemm64<<<g64, 256, 0, stream>>>(aob, 256, attnoutf, 256, attn_out_b,
                                  hidcat, 512, hidden32, 256, hT, B_,
                                  B_, 256, 256);
  // 6) GNN
  gemm64<<<g64, 256, 0, stream>>>(adjn, 1024, hT, 1024, nullptr,
                                  aggf, 256, nullptr, 0, nullptr, 0,
                                  B_, 256, 1024);
  gemm64<<<g64, 256, 0, stream>>>(aggf, 256, gnnwf, 256, gnn_b,
                                  nullptr, 0, gnnpre, 256, nullptr, 0,
                                  B_, 256, 256);
  gelu_ln_kernel<<<B_, 256, 0, stream>>>(gnnpre, ln_g, ln_b, enr32, hidcat);
  // 7) gate + output
  gemm64<<<g64, 256, 0, stream>>>(hidcat, 512, gatewf, 512, gate_b,
                                  nullptr, 0, gatepre, 256, nullptr, 0,
                                  B_, 256, 512);
  final_kernel<<<B_, 256, 0, stream>>>(gatepre, enr32, hidden32, out_w, out_b, (float*)d_out);
}